// Round 13
// baseline (3977.314 us; speedup 1.0000x reference)
//
#include <hip/hip_runtime.h>

#define BB 8
#define SS 1024
#define LL 12
#define DD 768
#define HH 12
#define FF 3072
#define VV 21128
#define DH 64
#define CLEN 960
#define NROWS (BB * CLEN)        // 7680 classifier rows
#define TOKS (BB * SS)           // 8192 token rows
#define NQKV 2304                // fused QKV output width
#define QKW 1536                 // qkbuf row width (Q|K)

typedef __attribute__((ext_vector_type(8))) short bh8;
typedef __attribute__((ext_vector_type(4))) float f32x4;
typedef __attribute__((ext_vector_type(4))) unsigned short us4;

__device__ __forceinline__ float bf2f(unsigned short u) {
    union { unsigned int i; float f; } c; c.i = ((unsigned int)u) << 16; return c.f;
}
__device__ __forceinline__ unsigned short f2bf(float f) {
    union { float f; unsigned int i; } c; c.f = f;
    unsigned int r = c.i + 0x7fffu + ((c.i >> 16) & 1u);
    return (unsigned short)(r >> 16);
}

#define GLOAD16(gsrc, ldst)                                                              \
    __builtin_amdgcn_global_load_lds((const __attribute__((address_space(1))) unsigned int*)(gsrc), \
                                     (__attribute__((address_space(3))) unsigned int*)(ldst), 16, 0, 0)

// 256-thread block sum; red must be shared float[4]
__device__ __forceinline__ float bsum256(float v, float* red) {
#pragma unroll
    for (int o = 32; o; o >>= 1) v += __shfl_down(v, o);
    if ((threadIdx.x & 63) == 0) red[threadIdx.x >> 6] = v;
    __syncthreads();
    float r = red[0] + red[1] + red[2] + red[3];
    __syncthreads();
    return r;
}

// ---------------- transpose fp32 [R,C] -> bf16 [C,R] (classifier) ----------------
__global__ void transpose_f32_bf16(const float* __restrict__ in, unsigned short* __restrict__ out,
                                   int R, int C) {
    __shared__ float tile[32][33];
    int c0 = blockIdx.x << 5, r0 = blockIdx.y << 5;
    int tx = threadIdx.x, ty = threadIdx.y;
    for (int i = ty; i < 32; i += 8) {
        int r = r0 + i, c = c0 + tx;
        if (r < R && c < C) tile[i][tx] = in[(size_t)r * C + c];
    }
    __syncthreads();
    for (int i = ty; i < 32; i += 8) {
        int oc = c0 + i, orr = r0 + tx;
        if (oc < C && orr < R) out[(size_t)oc * R + orr] = f2bf(tile[tx][i]);
    }
}

// ---------------- batched per-layer weight transpose: 1 dispatch per layer ----------------
// (kept per-layer deliberately: just-written transposed weights are L2/L3-hot when
//  the layer's GEMMs consume them — upfront transpose_all regressed R10/R11.)
__global__ void transpose_layer(const float* __restrict__ Wq, const float* __restrict__ Wk,
                                const float* __restrict__ Wv, const float* __restrict__ Wo,
                                const float* __restrict__ W1, const float* __restrict__ W2,
                                unsigned short* __restrict__ wqkvT, unsigned short* __restrict__ woT,
                                unsigned short* __restrict__ w1T, unsigned short* __restrict__ w2T) {
    __shared__ float tile[32][33];
    int t = blockIdx.x;
    const float* src;
    unsigned short* dst;
    int R, C, txt, tt;
    if (t < 1728) {
        int which = t / 576; tt = t % 576;
        src = which == 0 ? Wq : (which == 1 ? Wk : Wv);
        dst = wqkvT + (size_t)which * DD * DD; R = DD; C = DD; txt = 24;
    } else if (t < 2304) {
        tt = t - 1728; src = Wo; dst = woT; R = DD; C = DD; txt = 24;
    } else if (t < 4608) {
        tt = t - 2304; src = W1; dst = w1T; R = DD; C = FF; txt = 96;
    } else {
        tt = t - 4608; src = W2; dst = w2T; R = FF; C = DD; txt = 24;
    }
    int c0 = (tt % txt) << 5, r0 = (tt / txt) << 5;
    int tx = threadIdx.x, ty = threadIdx.y;
    for (int i = ty; i < 32; i += 8) tile[i][tx] = src[(size_t)(r0 + i) * C + c0 + tx];
    __syncthreads();
    for (int i = ty; i < 32; i += 8) dst[(size_t)(c0 + i) * R + r0 + tx] = f2bf(tile[tx][i]);
}

// all-layer QKV bias concat
__global__ void concat_bias_all(const float* __restrict__ bq, const float* __restrict__ bk,
                                const float* __restrict__ bv, float* __restrict__ out) {
    int i = blockIdx.x * 256 + threadIdx.x;
    if (i >= LL * NQKV) return;
    int l = i / NQKV, c = i % NQKV;
    float v = c < DD ? bq[(size_t)l * DD + c]
                     : (c < 2 * DD ? bk[(size_t)l * DD + c - DD] : bv[(size_t)l * DD + c - 2 * DD]);
    out[i] = v;
}

// ---------------- embedding + LN -> bf16 (LN-out == residual stream) ----------------
__global__ __launch_bounds__(256) void embed_ln(const int* __restrict__ x, const float* __restrict__ we,
                                                const float* __restrict__ pe, const float* __restrict__ te,
                                                const float* __restrict__ g, const float* __restrict__ be,
                                                unsigned short* __restrict__ hb) {
    int row = blockIdx.x;            // b*S + s
    int s = row & (SS - 1);
    int tok = x[row];
    int tid = threadIdx.x;
    __shared__ float red[4];
    float v[3];
#pragma unroll
    for (int i = 0; i < 3; i++) {
        int c = tid + i * 256;
        v[i] = we[(size_t)tok * DD + c] + pe[(size_t)s * DD + c] + te[c];
    }
    float mean = bsum256(v[0] + v[1] + v[2], red) * (1.f / DD);
    float d0 = v[0] - mean, d1 = v[1] - mean, d2 = v[2] - mean;
    float var = bsum256(d0 * d0 + d1 * d1 + d2 * d2, red) * (1.f / DD);
    float inv = rsqrtf(var + 1e-12f);
    size_t base = (size_t)row * DD;
#pragma unroll
    for (int i = 0; i < 3; i++) {
        int c = tid + i * 256;
        hb[base + c] = f2bf((v[i] - mean) * inv * g[c] + be[c]);
    }
}

// ---------------- residual add (bf16) + LN -> bf16 ----------------
__global__ __launch_bounds__(256) void add_ln(const unsigned short* __restrict__ res,
                                              const unsigned short* __restrict__ t,
                                              const float* __restrict__ g, const float* __restrict__ be,
                                              unsigned short* __restrict__ outb) {
    int row = blockIdx.x;
    int tid = threadIdx.x;
    __shared__ float red[4];
    size_t base = (size_t)row * DD;
    float v[3];
#pragma unroll
    for (int i = 0; i < 3; i++) {
        int c = tid + i * 256;
        v[i] = bf2f(res[base + c]) + bf2f(t[base + c]);
    }
    float mean = bsum256(v[0] + v[1] + v[2], red) * (1.f / DD);
    float d0 = v[0] - mean, d1 = v[1] - mean, d2 = v[2] - mean;
    float var = bsum256(d0 * d0 + d1 * d1 + d2 * d2, red) * (1.f / DD);
    float inv = rsqrtf(var + 1e-12f);
#pragma unroll
    for (int i = 0; i < 3; i++) {
        int c = tid + i * 256;
        outb[base + c] = f2bf((v[i] - mean) * inv * g[c] + be[c]);
    }
}

// ---------------- MFMA GEMM: 128x128 tile, BK=32, double-buffered 2-phase ----------------
// Block-order remap: XCD-bijective chunk + m-bands of SM tiles walked n-major (L2 reuse).
// MODE 1: bf16 out; 2: bf16 + exact GELU; 3: fused classifier LSE; 4: fused QKV epilogue
template <int MODE>
__global__ __launch_bounds__(256) void gemm128(const unsigned short* __restrict__ A,
                                               const unsigned short* __restrict__ BT,
                                               const float* __restrict__ bias, void* __restrict__ Cp,
                                               int M, int N, int K, int ldc, int SM,
                                               unsigned short* __restrict__ vt_out,
                                               const int* __restrict__ yv,
                                               float* __restrict__ stS, float* __restrict__ stT) {
    __shared__ __align__(16) unsigned short As[2][128 * 32];
    __shared__ __align__(16) unsigned short Bs[2][128 * 32];
    const int tid = threadIdx.x;
    const int lane = tid & 63, w = tid >> 6;
    const int fr = lane & 15, fg = lane >> 4;
    const int wr = w >> 1, wc = w & 1;

    // ---- schedule remap ----
    const int Nt = gridDim.x;
    const int flat = blockIdx.y * Nt + blockIdx.x;
    const int per8 = (Nt * gridDim.y) >> 3;
    const int virt = (flat & 7) * per8 + (flat >> 3);
    const int bandSz = SM * Nt;
    const int band = virt / bandSz, rem = virt - band * bandSz;
    const int nt = rem / SM;
    const int mt = band * SM + (rem - nt * SM);
    const int m0 = mt << 7, n0 = nt << 7;

    const int srow = lane >> 2;
    const int skcol = (lane & 3) << 3;

    int arow0 = m0 + (w * 2 + 0) * 16 + srow;
    int arow1 = m0 + (w * 2 + 1) * 16 + srow;
    int brow0 = n0 + (w * 2 + 0) * 16 + srow;
    int brow1 = n0 + (w * 2 + 1) * 16 + srow;
    if (brow0 >= N) brow0 = N - 1;       // clamp (classifier tail); epilogue guarded
    if (brow1 >= N) brow1 = N - 1;
    const unsigned short* aptr0 = A + (size_t)arow0 * K + skcol;
    const unsigned short* aptr1 = A + (size_t)arow1 * K + skcol;
    const unsigned short* bptr0 = BT + (size_t)brow0 * K + skcol;
    const unsigned short* bptr1 = BT + (size_t)brow1 * K + skcol;

    auto stage = [&](int bf, int k0) {
        GLOAD16(aptr0 + k0, &As[bf][(w * 2 + 0) * 512]);
        GLOAD16(aptr1 + k0, &As[bf][(w * 2 + 1) * 512]);
        GLOAD16(bptr0 + k0, &Bs[bf][(w * 2 + 0) * 512]);
        GLOAD16(bptr1 + k0, &Bs[bf][(w * 2 + 1) * 512]);
    };

    f32x4 acc[4][4] = {};
    stage(0, 0);
    __syncthreads();      // compiler drains vmcnt(0) before barrier
    int cur = 0;
    for (int k0 = 0; k0 < K; k0 += 32) {
        if (k0 + 32 < K) stage(cur ^ 1, k0 + 32);   // prefetch overlaps compute
        bh8 a[4], b[4];
#pragma unroll
        for (int mi = 0; mi < 4; mi++) a[mi] = *(const bh8*)&As[cur][(wr * 64 + mi * 16 + fr) * 32 + fg * 8];
#pragma unroll
        for (int ni = 0; ni < 4; ni++) b[ni] = *(const bh8*)&Bs[cur][(wc * 64 + ni * 16 + fr) * 32 + fg * 8];
        __builtin_amdgcn_s_setprio(1);
#pragma unroll
        for (int mi = 0; mi < 4; mi++)
#pragma unroll
            for (int ni = 0; ni < 4; ni++)
                acc[mi][ni] = __builtin_amdgcn_mfma_f32_16x16x32_bf16(a[mi], b[ni], acc[mi][ni], 0, 0, 0);
        __builtin_amdgcn_s_setprio(0);
        __syncthreads();
        cur ^= 1;
    }

    unsigned short* Cb = (unsigned short*)Cp;
#pragma unroll
    for (int mi = 0; mi < 4; mi++) {
        int rbase = m0 + wr * 64 + mi * 16 + fg * 4;
        if (MODE == 3) {
            // fused classifier LSE: logits bounded -> max-free sumexp fp32-safe.
            float e[4] = {0.f, 0.f, 0.f, 0.f};
            int yr[4];
#pragma unroll
            for (int r = 0; r < 4; r++) yr[r] = yv[rbase + r];
#pragma unroll
            for (int ni = 0; ni < 4; ni++) {
                int col = n0 + wc * 64 + ni * 16 + fr;
                if (col < N) {
                    float bb = bias[col];
#pragma unroll
                    for (int r = 0; r < 4; r++) {
                        float v = acc[mi][ni][r] + bb;
                        e[r] += __expf(v);
                        if (col == yr[r]) stT[rbase + r] = v;   // unique writer
                    }
                }
            }
#pragma unroll
            for (int r = 0; r < 4; r++) {
#pragma unroll
                for (int off = 1; off < 16; off <<= 1) e[r] += __shfl_xor(e[r], off);
                if (fr == 0) atomicAdd(&stS[rbase + r], e[r]);
            }
        } else {
#pragma unroll
            for (int ni = 0; ni < 4; ni++) {
                int col = n0 + wc * 64 + ni * 16 + fr;
                if (MODE == 4) {
                    float bb = bias[col];
                    if (col < 2 * DD) {
#pragma unroll
                        for (int r = 0; r < 4; r++)
                            Cb[(size_t)(rbase + r) * QKW + col] = f2bf(acc[mi][ni][r] + bb);
                    } else {
                        int g = col - 2 * DD, h = g >> 6, d = g & 63;
                        int bi = rbase >> 10, s0 = rbase & 1023;
                        us4 val;
#pragma unroll
                        for (int r = 0; r < 4; r++) val[r] = f2bf(acc[mi][ni][r] + bb);
                        *(us4*)&vt_out[(((size_t)bi * HH + h) * DH + d) * SS + s0] = val;
                    }
                } else if (col < N) {
                    float bb = bias[col];
#pragma unroll
                    for (int r = 0; r < 4; r++) {
                        float v = acc[mi][ni][r] + bb;
                        if (MODE == 2) v = 0.5f * v * (1.0f + erff(v * 0.70710678118f));
                        Cb[(size_t)(rbase + r) * ldc + col] = f2bf(v);
                    }
                }
            }
        }
    }
}

// ---------------- flash attention: KVBLK=128, paired Q-tiles, Q in registers ----------------
// grid (8, H, B) = 768 blocks. Block bx: qt = 15-bx then qt = bx; tiles(15-bx)+tiles(bx) = 9
// for every bx (tiles(qt) = ceil((qt+1)/2)). Tile-steps/barriers ~halved vs KVBLK=64.
// LDS 51.2 KB (no Q) -> 3 blocks/CU. Mask (last tile only): key > max(q, 63).
__global__ __launch_bounds__(256) void flash_attn(const unsigned short* __restrict__ qkbuf,
                                                  const unsigned short* __restrict__ VT,
                                                  unsigned short* __restrict__ ctxb) {
    const int bx = blockIdx.x;
    const int h = blockIdx.y, b = blockIdx.z;
    const int tid = threadIdx.x;
    const int lane = tid & 63, w = tid >> 6;
    const int fr = lane & 15, fg = lane >> 4;
    __shared__ unsigned short Ks[128][68];      // [key][d]
    __shared__ unsigned short Vt[64][132];      // [d][key]
    __shared__ unsigned short Ps[4][16][132];   // per-wave P [q][key]

    // staging assignment: K row tid>>1, col-half (tid&1)*32 ; V row tid>>2, key-quarter (tid&3)*32
    const int krow = tid >> 1, kcol = (tid & 1) << 5;
    const int vrow = tid >> 2, vcol = (tid & 3) << 5;
    const unsigned short* kbase = qkbuf + (size_t)(b * SS + krow) * QKW + DD + h * 64 + kcol;
    const unsigned short* vbase = VT + ((size_t)(b * HH + h) * DH + vrow) * SS + vcol;

    bh8 kr[4], vr[4];
    auto ld_reg = [&](int kt) {
        const unsigned short* ks = kbase + (size_t)(kt * 128) * QKW;
#pragma unroll
        for (int j = 0; j < 4; j++) kr[j] = *(const bh8*)(ks + j * 8);
        const unsigned short* vs = vbase + kt * 128;
#pragma unroll
        for (int j = 0; j < 4; j++) vr[j] = *(const bh8*)(vs + j * 8);
    };

    for (int half = 0; half < 2; half++) {
        const int qt = (half == 0) ? 15 - bx : bx;
        const int nkt = (qt + 2) >> 1;          // ceil((qt+1)/2)
        const int qrow_g = qt * 64 + w * 16 + fr;

        // Q fragments direct from global (no LDS)
        const unsigned short* qr = qkbuf + (size_t)(b * SS + qrow_g) * QKW + h * 64 + fg * 8;
        const bh8 a0 = *(const bh8*)qr;
        const bh8 a1 = *(const bh8*)(qr + 32);

        f32x4 o[4] = {};
        float m[4], l[4];
#pragma unroll
        for (int r = 0; r < 4; r++) { m[r] = -3e30f; l[r] = 0.f; }

        ld_reg(0);
        for (int kt = 0; kt < nkt; kt++) {
            __syncthreads();   // (a) previous tile's (or half's) LDS readers done
#pragma unroll
            for (int j = 0; j < 4; j++) *(bh8*)&Ks[krow][kcol + j * 8] = kr[j];
#pragma unroll
            for (int j = 0; j < 4; j++) *(bh8*)&Vt[vrow][vcol + j * 8] = vr[j];
            if (kt + 1 < nkt) ld_reg(kt + 1);   // in flight under this tile's compute
            __syncthreads();   // (b) K/V visible

            // QK^T: 128 keys = 8 col-frags
            f32x4 s[8] = {};
            __builtin_amdgcn_s_setprio(1);
#pragma unroll
            for (int cf = 0; cf < 8; cf++) {
                bh8 b0 = *(const bh8*)&Ks[cf * 16 + fr][fg * 8];
                bh8 b1 = *(const bh8*)&Ks[cf * 16 + fr][32 + fg * 8];
                s[cf] = __builtin_amdgcn_mfma_f32_16x16x32_bf16(a0, b0, s[cf], 0, 0, 0);
                s[cf] = __builtin_amdgcn_mfma_f32_16x16x32_bf16(a1, b1, s[cf], 0, 0, 0);
            }
            __builtin_amdgcn_s_setprio(0);

            const bool lastT = (kt == nkt - 1);
#pragma unroll
            for (int cf = 0; cf < 8; cf++) {
#pragma unroll
                for (int r = 0; r < 4; r++) {
                    float v = s[cf][r] * 0.125f;
                    if (lastT) {
                        int key = kt * 128 + cf * 16 + fr;
                        int q = qt * 64 + w * 16 + fg * 4 + r;
                        int lim = q < 64 ? 63 : q;
                        if (key > lim) v = -1e30f;
                    }
                    s[cf][r] = v;
                }
            }
            // online softmax (row stats across 16-lane group)
            float sc[4], mn[4];
#pragma unroll
            for (int r = 0; r < 4; r++) {
                float v = s[0][r];
#pragma unroll
                for (int cf = 1; cf < 8; cf++) v = fmaxf(v, s[cf][r]);
#pragma unroll
                for (int off = 1; off < 16; off <<= 1) v = fmaxf(v, __shfl_xor(v, off));
                mn[r] = fmaxf(m[r], v);
                sc[r] = __expf(m[r] - mn[r]);
                m[r] = mn[r];
            }
#pragma unroll
            for (int cf = 0; cf < 8; cf++) {
#pragma unroll
                for (int r = 0; r < 4; r++) s[cf][r] = __expf(s[cf][r] - mn[r]);
            }
#pragma unroll
            for (int r = 0; r < 4; r++) {
                float v = s[0][r];
#pragma unroll
                for (int cf = 1; cf < 8; cf++) v += s[cf][r];
#pragma unroll
                for (int off = 1; off < 16; off <<= 1) v += __shfl_xor(v, off);
                l[r] = l[r] * sc[r] + v;
            }
#pragma unroll
            for (int df = 0; df < 4; df++) {
#pragma unroll
                for (int r = 0; r < 4; r++) o[df][r] *= sc[r];
            }
            // P -> per-wave LDS
#pragma unroll
            for (int cf = 0; cf < 8; cf++) {
#pragma unroll
                for (int r = 0; r < 4; r++) Ps[w][fg * 4 + r][cf * 16 + fr] = f2bf(s[cf][r]);
            }
            bh8 pa[4];
#pragma unroll
            for (int kk = 0; kk < 4; kk++) pa[kk] = *(const bh8*)&Ps[w][fr][kk * 32 + fg * 8];
            __builtin_amdgcn_s_setprio(1);
#pragma unroll
            for (int df = 0; df < 4; df++) {
#pragma unroll
                for (int kk = 0; kk < 4; kk++) {
                    bh8 vb = *(const bh8*)&Vt[df * 16 + fr][kk * 32 + fg * 8];
                    o[df] = __builtin_amdgcn_mfma_f32_16x16x32_bf16(pa[kk], vb, o[df], 0, 0, 0);
                }
            }
            __builtin_amdgcn_s_setprio(0);
        }
#pragma unroll
        for (int df = 0; df < 4; df++) {
#pragma unroll
            for (int r = 0; r < 4; r++) {
                int q = qt * 64 + w * 16 + fg * 4 + r;
                float v = o[df][r] / l[r];
                ctxb[(((size_t)b * SS + q) * HH + h) * DH + df * 16 + fr] = f2bf(v);
            }
        }
    }
}

// ---------------- gather classifier rows + init LSE state ----------------
__global__ void gather_rows(const unsigned short* __restrict__ hb, unsigned short* __restrict__ hc,
                            float* __restrict__ stS, float* __restrict__ stT) {
    int idx = blockIdx.x * 256 + threadIdx.x;
    if (idx < NROWS) { stS[idx] = 0.f; stT[idx] = 0.f; }
    if (idx >= NROWS * (DD / 8)) return;
    int g = idx / (DD / 8), c8 = (idx % (DD / 8)) * 8;
    int b = g / CLEN, cc = g % CLEN;
    *(bh8*)&hc[(size_t)g * DD + c8] = *(const bh8*)&hb[((size_t)(b * SS + 64 + cc)) * DD + c8];
}

__global__ __launch_bounds__(256) void final_reduce(const float* __restrict__ stS,
                                                    const float* __restrict__ stT, const int* __restrict__ y,
                                                    float* __restrict__ out) {
    int tid = threadIdx.x;
    float s = 0.f, c = 0.f;
    for (int i = tid; i < NROWS; i += 256) {
        if (y[i] != -100) {
            s += logf(stS[i]) - stT[i];
            c += 1.f;
        }
    }
    __shared__ float red[4];
    float gs = bsum256(s, red);
    float gc = bsum256(c, red);
    if (tid == 0) out[0] = gs / fmaxf(gc, 1.f);
}

// ---------------- launcher ----------------
extern "C" void kernel_launch(void* const* d_in, const int* in_sizes, int n_in,
                              void* d_out, int out_size, void* d_ws, size_t ws_size,
                              hipStream_t stream) {
    const int* x = (const int*)d_in[0];
    const int* y = (const int*)d_in[1];
    const float* we = (const float*)d_in[2];
    const float* pe = (const float*)d_in[3];
    const float* te = (const float*)d_in[4];
    const float* eg = (const float*)d_in[5];
    const float* eb = (const float*)d_in[6];
    const float* Wq = (const float*)d_in[7];
    const float* bq = (const float*)d_in[8];
    const float* Wk = (const float*)d_in[9];
    const float* bk = (const float*)d_in[10];
    const float* Wv = (const float*)d_in[11];
    const float* bv = (const float*)d_in[12];
    const float* Wo = (const float*)d_in[13];
    const float* bo = (const float*)d_in[14];
    const float* g1 = (const float*)d_in[15];
    const float* b1n = (const float*)d_in[16];
    const float* W1 = (const float*)d_in[17];
    const float* b1 = (const float*)d_in[18];
    const float* W2 = (const float*)d_in[19];
    const float* b2 = (const float*)d_in[20];
    const float* g2 = (const float*)d_in[21];
    const float* b2n = (const float*)d_in[22];
    const float* clsW = (const float*)d_in[23];
    const float* clsb = (const float*)d_in[24];
    float* out = (float*)d_out;

    char* ws = (char*)d_ws;
    size_t off = 0;
    auto alloc = [&](size_t n) {
        void* p = ws + off;
        off += n;
        off = (off + 255) & ~(size_t)255;
        return p;
    };
    unsigned short* hb   = (unsigned short*)alloc((size_t)TOKS * DD * 2);
    unsigned short* h1b  = (unsigned short*)alloc((size_t)TOKS * DD * 2);
    unsigned short* tmpb = (unsigned short*)alloc((size_t)TOKS * DD * 2);
    unsigned short* qkbuf = (unsigned short*)alloc((size_t)TOKS * QKW * 2);
    unsigned short* vtb  = (unsigned short*)alloc((size_t)TOKS * DD * 2);
    unsigned short* ctxb = (unsigned short*)alloc((size_t)TOKS * DD * 2);
    unsigned short* ffnb = (unsigned short*)alloc((size_t)TOKS * FF * 2);
    unsigned short* wqkvT = (unsigned short*)alloc((size_t)NQKV * DD * 2);
    unsigned short* woT = (unsigned short*)alloc((size_t)DD * DD * 2);
    unsigned short* w1T = (unsigned short*)alloc((size_t)DD * FF * 2);
    unsigned short* w2T = (unsigned short*)alloc((size_t)DD * FF * 2);
    unsigned short* clsT = (unsigned short*)alloc((size_t)VV * DD * 2);
    unsigned short* hc = (unsigned short*)alloc((size_t)NROWS * DD * 2);
    float* bqkv = (float*)alloc((size_t)LL * NQKV * 4);
    float* stS = (float*)alloc(NROWS * 4);
    float* stT = (float*)alloc(NROWS * 4);

    dim3 tb(32, 8);
    transpose_f32_bf16<<<dim3((VV + 31) / 32, DD / 32), tb, 0, stream>>>(clsW, clsT, DD, VV);
    concat_bias_all<<<(LL * NQKV + 255) / 256, 256, 0, stream>>>(bq, bk, bv, bqkv);
    embed_ln<<<TOKS, 256, 0, stream>>>(x, we, pe, te, eg, eb, hb);

    for (int l = 0; l < LL; l++) {
        transpose_layer<<<6912, tb, 0, stream>>>(Wq + (size_t)l * DD * DD, Wk + (size_t)l * DD * DD,
                                                 Wv + (size_t)l * DD * DD, Wo + (size_t)l * DD * DD,
                                                 W1 + (size_t)l * DD * FF, W2 + (size_t)l * FF * DD,
                                                 wqkvT, woT, w1T, w2T);

        gemm128<4><<<dim3(NQKV / 128, TOKS / 128), 256, 0, stream>>>(
            hb, wqkvT, bqkv + (size_t)l * NQKV,
            qkbuf, TOKS, NQKV, DD, NQKV, 8, vtb, nullptr, nullptr, nullptr);

        flash_attn<<<dim3(8, HH, BB), 256, 0, stream>>>(qkbuf, vtb, ctxb);

        gemm128<1><<<dim3(DD / 128, TOKS / 128), 256, 0, stream>>>(
            ctxb, woT, bo + (size_t)l * DD, tmpb,
            TOKS, DD, DD, DD, 8, nullptr, nullptr, nullptr, nullptr);
        add_ln<<<TOKS, 256, 0, stream>>>(hb, tmpb, g1 + (size_t)l * DD, b1n + (size_t)l * DD, h1b);

        gemm128<2><<<dim3(FF / 128, TOKS / 128), 256, 0, stream>>>(
            h1b, w1T, b1 + (size_t)l * FF, ffnb,
            TOKS, FF, DD, FF, 8, nullptr, nullptr, nullptr, nullptr);
        gemm128<1><<<dim3(DD / 128, TOKS / 128), 256, 0, stream>>>(
            ffnb, w2T, b2 + (size_t)l * DD, tmpb,
            TOKS, DD, FF, DD, 8, nullptr, nullptr, nullptr, nullptr);
        add_ln<<<TOKS, 256, 0, stream>>>(h1b, tmpb, g2 + (size_t)l * DD, b2n + (size_t)l * DD, hb);
    }

    gather_rows<<<(NROWS * (DD / 8) + 255) / 256, 256, 0, stream>>>(hb, hc, stS, stT);
    // single fused classifier GEMM + LSE; grid 166x60 = 9960 (%8==0), SM=6 (60%6==0)
    gemm128<3><<<dim3((VV + 127) / 128, NROWS / 128), 256, 0, stream>>>(hc, clsT, clsb, nullptr,
                                                                        NROWS, VV, DD, VV, 6, nullptr,
                                                                        y, stS, stT);
    final_reduce<<<1, 256, 0, stream>>>(stS, stT, y, out);
}

// Round 14
// 3852.746 us; speedup vs baseline: 1.0323x; 1.0323x over previous
//
#include <hip/hip_runtime.h>

#define BB 8
#define SS 1024
#define LL 12
#define DD 768
#define HH 12
#define FF 3072
#define VV 21128
#define DH 64
#define CLEN 960
#define NROWS (BB * CLEN)        // 7680 classifier rows
#define TOKS (BB * SS)           // 8192 token rows
#define NQKV 2304                // fused QKV output width
#define QKW 1536                 // qkbuf row width (Q|K)

typedef __attribute__((ext_vector_type(8))) short bh8;
typedef __attribute__((ext_vector_type(4))) float f32x4;
typedef __attribute__((ext_vector_type(4))) unsigned short us4;

__device__ __forceinline__ float bf2f(unsigned short u) {
    union { unsigned int i; float f; } c; c.i = ((unsigned int)u) << 16; return c.f;
}
__device__ __forceinline__ unsigned short f2bf(float f) {
    union { float f; unsigned int i; } c; c.f = f;
    unsigned int r = c.i + 0x7fffu + ((c.i >> 16) & 1u);
    return (unsigned short)(r >> 16);
}

#define GLOAD16(gsrc, ldst)                                                              \
    __builtin_amdgcn_global_load_lds((const __attribute__((address_space(1))) unsigned int*)(gsrc), \
                                     (__attribute__((address_space(3))) unsigned int*)(ldst), 16, 0, 0)

// 256-thread block sum; red must be shared float[4]
__device__ __forceinline__ float bsum256(float v, float* red) {
#pragma unroll
    for (int o = 32; o; o >>= 1) v += __shfl_down(v, o);
    if ((threadIdx.x & 63) == 0) red[threadIdx.x >> 6] = v;
    __syncthreads();
    float r = red[0] + red[1] + red[2] + red[3];
    __syncthreads();
    return r;
}

// ---------------- transpose fp32 [R,C] -> bf16 [C,R] (classifier) ----------------
__global__ void transpose_f32_bf16(const float* __restrict__ in, unsigned short* __restrict__ out,
                                   int R, int C) {
    __shared__ float tile[32][33];
    int c0 = blockIdx.x << 5, r0 = blockIdx.y << 5;
    int tx = threadIdx.x, ty = threadIdx.y;
    for (int i = ty; i < 32; i += 8) {
        int r = r0 + i, c = c0 + tx;
        if (r < R && c < C) tile[i][tx] = in[(size_t)r * C + c];
    }
    __syncthreads();
    for (int i = ty; i < 32; i += 8) {
        int oc = c0 + i, orr = r0 + tx;
        if (oc < C && orr < R) out[(size_t)oc * R + orr] = f2bf(tile[tx][i]);
    }
}

// ---------------- batched per-layer weight transpose: 1 dispatch per layer ----------------
// (kept per-layer deliberately: just-written transposed weights are L2/L3-hot when
//  the layer's GEMMs consume them — upfront transpose_all regressed R10/R11.)
__global__ void transpose_layer(const float* __restrict__ Wq, const float* __restrict__ Wk,
                                const float* __restrict__ Wv, const float* __restrict__ Wo,
                                const float* __restrict__ W1, const float* __restrict__ W2,
                                unsigned short* __restrict__ wqkvT, unsigned short* __restrict__ woT,
                                unsigned short* __restrict__ w1T, unsigned short* __restrict__ w2T) {
    __shared__ float tile[32][33];
    int t = blockIdx.x;
    const float* src;
    unsigned short* dst;
    int R, C, txt, tt;
    if (t < 1728) {
        int which = t / 576; tt = t % 576;
        src = which == 0 ? Wq : (which == 1 ? Wk : Wv);
        dst = wqkvT + (size_t)which * DD * DD; R = DD; C = DD; txt = 24;
    } else if (t < 2304) {
        tt = t - 1728; src = Wo; dst = woT; R = DD; C = DD; txt = 24;
    } else if (t < 4608) {
        tt = t - 2304; src = W1; dst = w1T; R = DD; C = FF; txt = 96;
    } else {
        tt = t - 4608; src = W2; dst = w2T; R = FF; C = DD; txt = 24;
    }
    int c0 = (tt % txt) << 5, r0 = (tt / txt) << 5;
    int tx = threadIdx.x, ty = threadIdx.y;
    for (int i = ty; i < 32; i += 8) tile[i][tx] = src[(size_t)(r0 + i) * C + c0 + tx];
    __syncthreads();
    for (int i = ty; i < 32; i += 8) dst[(size_t)(c0 + i) * R + r0 + tx] = f2bf(tile[tx][i]);
}

// all-layer QKV bias concat
__global__ void concat_bias_all(const float* __restrict__ bq, const float* __restrict__ bk,
                                const float* __restrict__ bv, float* __restrict__ out) {
    int i = blockIdx.x * 256 + threadIdx.x;
    if (i >= LL * NQKV) return;
    int l = i / NQKV, c = i % NQKV;
    float v = c < DD ? bq[(size_t)l * DD + c]
                     : (c < 2 * DD ? bk[(size_t)l * DD + c - DD] : bv[(size_t)l * DD + c - 2 * DD]);
    out[i] = v;
}

// ---------------- embedding + LN -> bf16 (LN-out == residual stream) ----------------
__global__ __launch_bounds__(256) void embed_ln(const int* __restrict__ x, const float* __restrict__ we,
                                                const float* __restrict__ pe, const float* __restrict__ te,
                                                const float* __restrict__ g, const float* __restrict__ be,
                                                unsigned short* __restrict__ hb) {
    int row = blockIdx.x;            // b*S + s
    int s = row & (SS - 1);
    int tok = x[row];
    int tid = threadIdx.x;
    __shared__ float red[4];
    float v[3];
#pragma unroll
    for (int i = 0; i < 3; i++) {
        int c = tid + i * 256;
        v[i] = we[(size_t)tok * DD + c] + pe[(size_t)s * DD + c] + te[c];
    }
    float mean = bsum256(v[0] + v[1] + v[2], red) * (1.f / DD);
    float d0 = v[0] - mean, d1 = v[1] - mean, d2 = v[2] - mean;
    float var = bsum256(d0 * d0 + d1 * d1 + d2 * d2, red) * (1.f / DD);
    float inv = rsqrtf(var + 1e-12f);
    size_t base = (size_t)row * DD;
#pragma unroll
    for (int i = 0; i < 3; i++) {
        int c = tid + i * 256;
        hb[base + c] = f2bf((v[i] - mean) * inv * g[c] + be[c]);
    }
}

// ---------------- residual add (bf16) + LN -> bf16, VECTORIZED (G13/m146) ----------------
// 128 threads/block, 96 active lanes each own 8 contiguous cols (bh8 loads/stores).
__global__ __launch_bounds__(128) void add_ln(const unsigned short* __restrict__ res,
                                              const unsigned short* __restrict__ t,
                                              const float* __restrict__ g, const float* __restrict__ be,
                                              unsigned short* __restrict__ outb) {
    const int row = blockIdx.x;
    const int tid = threadIdx.x;
    __shared__ float red[2];
    const size_t base = (size_t)row * DD;
    float v[8];
    float s = 0.f;
    if (tid < 96) {
        bh8 a = *(const bh8*)&res[base + tid * 8];
        bh8 b = *(const bh8*)&t[base + tid * 8];
#pragma unroll
        for (int j = 0; j < 8; j++) {
            v[j] = bf2f((unsigned short)a[j]) + bf2f((unsigned short)b[j]);
            s += v[j];
        }
    }
#pragma unroll
    for (int o = 32; o; o >>= 1) s += __shfl_down(s, o);
    if ((tid & 63) == 0) red[tid >> 6] = s;
    __syncthreads();
    const float mean = (red[0] + red[1]) * (1.f / DD);
    __syncthreads();
    float vs = 0.f;
    if (tid < 96) {
#pragma unroll
        for (int j = 0; j < 8; j++) {
            float d = v[j] - mean;
            vs += d * d;
        }
    }
#pragma unroll
    for (int o = 32; o; o >>= 1) vs += __shfl_down(vs, o);
    if ((tid & 63) == 0) red[tid >> 6] = vs;
    __syncthreads();
    const float inv = rsqrtf((red[0] + red[1]) * (1.f / DD) + 1e-12f);
    if (tid < 96) {
        bh8 o8;
#pragma unroll
        for (int j = 0; j < 8; j++) {
            int c = tid * 8 + j;
            o8[j] = (short)f2bf((v[j] - mean) * inv * g[c] + be[c]);
        }
        *(bh8*)&outb[base + tid * 8] = o8;
    }
}

// ---------------- MFMA GEMM: 128x128 tile, BK=32, double-buffered 2-phase ----------------
// Block-order remap: XCD-bijective chunk + m-bands of SM tiles walked n-major (L2 reuse).
// MODE 1: bf16 out; 2: bf16 + exact GELU; 3: fused classifier LSE; 4: fused QKV epilogue
template <int MODE>
__global__ __launch_bounds__(256) void gemm128(const unsigned short* __restrict__ A,
                                               const unsigned short* __restrict__ BT,
                                               const float* __restrict__ bias, void* __restrict__ Cp,
                                               int M, int N, int K, int ldc, int SM,
                                               unsigned short* __restrict__ vt_out,
                                               const int* __restrict__ yv,
                                               float* __restrict__ stS, float* __restrict__ stT) {
    __shared__ __align__(16) unsigned short As[2][128 * 32];
    __shared__ __align__(16) unsigned short Bs[2][128 * 32];
    const int tid = threadIdx.x;
    const int lane = tid & 63, w = tid >> 6;
    const int fr = lane & 15, fg = lane >> 4;
    const int wr = w >> 1, wc = w & 1;

    // ---- schedule remap ----
    const int Nt = gridDim.x;
    const int flat = blockIdx.y * Nt + blockIdx.x;
    const int per8 = (Nt * gridDim.y) >> 3;
    const int virt = (flat & 7) * per8 + (flat >> 3);
    const int bandSz = SM * Nt;
    const int band = virt / bandSz, rem = virt - band * bandSz;
    const int nt = rem / SM;
    const int mt = band * SM + (rem - nt * SM);
    const int m0 = mt << 7, n0 = nt << 7;

    const int srow = lane >> 2;
    const int skcol = (lane & 3) << 3;

    int arow0 = m0 + (w * 2 + 0) * 16 + srow;
    int arow1 = m0 + (w * 2 + 1) * 16 + srow;
    int brow0 = n0 + (w * 2 + 0) * 16 + srow;
    int brow1 = n0 + (w * 2 + 1) * 16 + srow;
    if (brow0 >= N) brow0 = N - 1;       // clamp (classifier tail); epilogue guarded
    if (brow1 >= N) brow1 = N - 1;
    const unsigned short* aptr0 = A + (size_t)arow0 * K + skcol;
    const unsigned short* aptr1 = A + (size_t)arow1 * K + skcol;
    const unsigned short* bptr0 = BT + (size_t)brow0 * K + skcol;
    const unsigned short* bptr1 = BT + (size_t)brow1 * K + skcol;

    auto stage = [&](int bf, int k0) {
        GLOAD16(aptr0 + k0, &As[bf][(w * 2 + 0) * 512]);
        GLOAD16(aptr1 + k0, &As[bf][(w * 2 + 1) * 512]);
        GLOAD16(bptr0 + k0, &Bs[bf][(w * 2 + 0) * 512]);
        GLOAD16(bptr1 + k0, &Bs[bf][(w * 2 + 1) * 512]);
    };

    f32x4 acc[4][4] = {};
    stage(0, 0);
    __syncthreads();      // compiler drains vmcnt(0) before barrier
    int cur = 0;
    for (int k0 = 0; k0 < K; k0 += 32) {
        if (k0 + 32 < K) stage(cur ^ 1, k0 + 32);   // prefetch overlaps compute
        bh8 a[4], b[4];
#pragma unroll
        for (int mi = 0; mi < 4; mi++) a[mi] = *(const bh8*)&As[cur][(wr * 64 + mi * 16 + fr) * 32 + fg * 8];
#pragma unroll
        for (int ni = 0; ni < 4; ni++) b[ni] = *(const bh8*)&Bs[cur][(wc * 64 + ni * 16 + fr) * 32 + fg * 8];
        __builtin_amdgcn_s_setprio(1);
#pragma unroll
        for (int mi = 0; mi < 4; mi++)
#pragma unroll
            for (int ni = 0; ni < 4; ni++)
                acc[mi][ni] = __builtin_amdgcn_mfma_f32_16x16x32_bf16(a[mi], b[ni], acc[mi][ni], 0, 0, 0);
        __builtin_amdgcn_s_setprio(0);
        __syncthreads();
        cur ^= 1;
    }

    unsigned short* Cb = (unsigned short*)Cp;
#pragma unroll
    for (int mi = 0; mi < 4; mi++) {
        int rbase = m0 + wr * 64 + mi * 16 + fg * 4;
        if (MODE == 3) {
            // fused classifier LSE: logits bounded -> max-free sumexp fp32-safe.
            float e[4] = {0.f, 0.f, 0.f, 0.f};
            int yr[4];
#pragma unroll
            for (int r = 0; r < 4; r++) yr[r] = yv[rbase + r];
#pragma unroll
            for (int ni = 0; ni < 4; ni++) {
                int col = n0 + wc * 64 + ni * 16 + fr;
                if (col < N) {
                    float bb = bias[col];
#pragma unroll
                    for (int r = 0; r < 4; r++) {
                        float v = acc[mi][ni][r] + bb;
                        e[r] += __expf(v);
                        if (col == yr[r]) stT[rbase + r] = v;   // unique writer
                    }
                }
            }
#pragma unroll
            for (int r = 0; r < 4; r++) {
#pragma unroll
                for (int off = 1; off < 16; off <<= 1) e[r] += __shfl_xor(e[r], off);
                if (fr == 0) atomicAdd(&stS[rbase + r], e[r]);
            }
        } else {
#pragma unroll
            for (int ni = 0; ni < 4; ni++) {
                int col = n0 + wc * 64 + ni * 16 + fr;
                if (MODE == 4) {
                    float bb = bias[col];
                    if (col < 2 * DD) {
#pragma unroll
                        for (int r = 0; r < 4; r++)
                            Cb[(size_t)(rbase + r) * QKW + col] = f2bf(acc[mi][ni][r] + bb);
                    } else {
                        int g = col - 2 * DD, h = g >> 6, d = g & 63;
                        int bi = rbase >> 10, s0 = rbase & 1023;
                        us4 val;
#pragma unroll
                        for (int r = 0; r < 4; r++) val[r] = f2bf(acc[mi][ni][r] + bb);
                        *(us4*)&vt_out[(((size_t)bi * HH + h) * DH + d) * SS + s0] = val;
                    }
                } else if (col < N) {
                    float bb = bias[col];
#pragma unroll
                    for (int r = 0; r < 4; r++) {
                        float v = acc[mi][ni][r] + bb;
                        if (MODE == 2) v = 0.5f * v * (1.0f + erff(v * 0.70710678118f));
                        Cb[(size_t)(rbase + r) * ldc + col] = f2bf(v);
                    }
                }
            }
        }
    }
}

// ---------------- flash attention: paired Q-tiles for perfect load balance (R12-verified) ----
// grid (8, H, B) = 768 blocks, all co-resident. Block bx handles qt = 15-bx then qt = bx
// (every block = 17 tile-steps). Pad-68 LDS (conflict-free) + T14 register prefetch.
__global__ __launch_bounds__(256) void flash_attn(const unsigned short* __restrict__ qkbuf,
                                                  const unsigned short* __restrict__ VT,
                                                  unsigned short* __restrict__ ctxb) {
    const int bx = blockIdx.x;
    const int h = blockIdx.y, b = blockIdx.z;
    const int tid = threadIdx.x;
    const int lane = tid & 63, w = tid >> 6;
    const int fr = lane & 15, fg = lane >> 4;
    __shared__ unsigned short Qs[64][68];
    __shared__ unsigned short Ks[64][68];
    __shared__ unsigned short Vt[64][68];       // Vt[d][key]
    __shared__ unsigned short Ps[4][16][68];    // per-wave P [q][key]

    const int srow = tid >> 2, sd0 = (tid & 3) << 4;
    const unsigned short* kbase = qkbuf + (size_t)(b * SS + srow) * QKW + DD + h * 64 + sd0;
    const unsigned short* vbase = VT + (((size_t)b * HH + h) * DH + srow) * SS + sd0;

    bh8 kr0, kr1, vr0, vr1;
    auto ld_reg = [&](int kt) {
        const unsigned short* ks = kbase + (size_t)(kt * 64) * QKW;
        kr0 = *(const bh8*)ks;
        kr1 = *(const bh8*)(ks + 8);
        const unsigned short* vs = vbase + kt * 64;
        vr0 = *(const bh8*)vs;
        vr1 = *(const bh8*)(vs + 8);
    };

    for (int half = 0; half < 2; half++) {
        const int qt = (half == 0) ? 15 - bx : bx;
        __syncthreads();   // protect Qs/Ks/Vt from previous half's readers
        {
            const unsigned short* src = qkbuf + (size_t)(b * SS + qt * 64 + srow) * QKW + h * 64 + sd0;
            *(bh8*)&Qs[srow][sd0] = *(const bh8*)src;
            *(bh8*)&Qs[srow][sd0 + 8] = *(const bh8*)(src + 8);
        }

        f32x4 o[4] = {};
        float m[4], l[4];
#pragma unroll
        for (int r = 0; r < 4; r++) { m[r] = -3e30f; l[r] = 0.f; }

        const int nkt = (qt == 0) ? 1 : qt + 1;
        ld_reg(0);
        for (int kt = 0; kt < nkt; kt++) {
            __syncthreads();   // (a) prev tile's LDS reads complete
            *(bh8*)&Ks[srow][sd0] = kr0;
            *(bh8*)&Ks[srow][sd0 + 8] = kr1;
            *(bh8*)&Vt[srow][sd0] = vr0;
            *(bh8*)&Vt[srow][sd0 + 8] = vr1;
            if (kt + 1 < nkt) ld_reg(kt + 1);   // in flight under this tile's compute
            __syncthreads();   // (b) Q/K/V visible

            // QK^T
            f32x4 s[4] = {};
            bh8 a0 = *(const bh8*)&Qs[w * 16 + fr][fg * 8];
            bh8 a1 = *(const bh8*)&Qs[w * 16 + fr][32 + fg * 8];
            __builtin_amdgcn_s_setprio(1);
#pragma unroll
            for (int cf = 0; cf < 4; cf++) {
                bh8 b0 = *(const bh8*)&Ks[cf * 16 + fr][fg * 8];
                bh8 b1 = *(const bh8*)&Ks[cf * 16 + fr][32 + fg * 8];
                s[cf] = __builtin_amdgcn_mfma_f32_16x16x32_bf16(a0, b0, s[cf], 0, 0, 0);
                s[cf] = __builtin_amdgcn_mfma_f32_16x16x32_bf16(a1, b1, s[cf], 0, 0, 0);
            }
            __builtin_amdgcn_s_setprio(0);

            const bool diag = (qt > 0) && (kt == qt);
#pragma unroll
            for (int cf = 0; cf < 4; cf++) {
#pragma unroll
                for (int r = 0; r < 4; r++) {
                    float v = s[cf][r] * 0.125f;
                    if (diag) {
                        int key = cf * 16 + fr;
                        int qrow = w * 16 + fg * 4 + r;
                        if (key > qrow) v = -1e30f;
                    }
                    s[cf][r] = v;
                }
            }
            float sc[4], mn[4];
#pragma unroll
            for (int r = 0; r < 4; r++) {
                float v = fmaxf(fmaxf(s[0][r], s[1][r]), fmaxf(s[2][r], s[3][r]));
#pragma unroll
                for (int off = 1; off < 16; off <<= 1) v = fmaxf(v, __shfl_xor(v, off));
                mn[r] = fmaxf(m[r], v);
                sc[r] = __expf(m[r] - mn[r]);
                m[r] = mn[r];
            }
#pragma unroll
            for (int cf = 0; cf < 4; cf++) {
#pragma unroll
                for (int r = 0; r < 4; r++) s[cf][r] = __expf(s[cf][r] - mn[r]);
            }
#pragma unroll
            for (int r = 0; r < 4; r++) {
                float v = s[0][r] + s[1][r] + s[2][r] + s[3][r];
#pragma unroll
                for (int off = 1; off < 16; off <<= 1) v += __shfl_xor(v, off);
                l[r] = l[r] * sc[r] + v;
            }
#pragma unroll
            for (int df = 0; df < 4; df++) {
#pragma unroll
                for (int r = 0; r < 4; r++) o[df][r] *= sc[r];
            }
#pragma unroll
            for (int cf = 0; cf < 4; cf++) {
#pragma unroll
                for (int r = 0; r < 4; r++) Ps[w][fg * 4 + r][cf * 16 + fr] = f2bf(s[cf][r]);
            }
            bh8 pa0 = *(const bh8*)&Ps[w][fr][fg * 8];
            bh8 pa1 = *(const bh8*)&Ps[w][fr][32 + fg * 8];
            __builtin_amdgcn_s_setprio(1);
#pragma unroll
            for (int df = 0; df < 4; df++) {
                bh8 vb0 = *(const bh8*)&Vt[df * 16 + fr][fg * 8];
                bh8 vb1 = *(const bh8*)&Vt[df * 16 + fr][32 + fg * 8];
                o[df] = __builtin_amdgcn_mfma_f32_16x16x32_bf16(pa0, vb0, o[df], 0, 0, 0);
                o[df] = __builtin_amdgcn_mfma_f32_16x16x32_bf16(pa1, vb1, o[df], 0, 0, 0);
            }
            __builtin_amdgcn_s_setprio(0);
        }
#pragma unroll
        for (int df = 0; df < 4; df++) {
#pragma unroll
            for (int r = 0; r < 4; r++) {
                int q = qt * 64 + w * 16 + fg * 4 + r;
                float v = o[df][r] / l[r];
                ctxb[(((size_t)b * SS + q) * HH + h) * DH + df * 16 + fr] = f2bf(v);
            }
        }
    }
}

// ---------------- gather classifier rows + init LSE state ----------------
__global__ void gather_rows(const unsigned short* __restrict__ hb, unsigned short* __restrict__ hc,
                            float* __restrict__ stS, float* __restrict__ stT) {
    int idx = blockIdx.x * 256 + threadIdx.x;
    if (idx < NROWS) { stS[idx] = 0.f; stT[idx] = 0.f; }
    if (idx >= NROWS * (DD / 8)) return;
    int g = idx / (DD / 8), c8 = (idx % (DD / 8)) * 8;
    int b = g / CLEN, cc = g % CLEN;
    *(bh8*)&hc[(size_t)g * DD + c8] = *(const bh8*)&hb[((size_t)(b * SS + 64 + cc)) * DD + c8];
}

__global__ __launch_bounds__(256) void final_reduce(const float* __restrict__ stS,
                                                    const float* __restrict__ stT, const int* __restrict__ y,
                                                    float* __restrict__ out) {
    int tid = threadIdx.x;
    float s = 0.f, c = 0.f;
    for (int i = tid; i < NROWS; i += 256) {
        if (y[i] != -100) {
            s += logf(stS[i]) - stT[i];
            c += 1.f;
        }
    }
    __shared__ float red[4];
    float gs = bsum256(s, red);
    float gc = bsum256(c, red);
    if (tid == 0) out[0] = gs / fmaxf(gc, 1.f);
}

// ---------------- launcher ----------------
extern "C" void kernel_launch(void* const* d_in, const int* in_sizes, int n_in,
                              void* d_out, int out_size, void* d_ws, size_t ws_size,
                              hipStream_t stream) {
    const int* x = (const int*)d_in[0];
    const int* y = (const int*)d_in[1];
    const float* we = (const float*)d_in[2];
    const float* pe = (const float*)d_in[3];
    const float* te = (const float*)d_in[4];
    const float* eg = (const float*)d_in[5];
    const float* eb = (const float*)d_in[6];
    const float* Wq = (const float*)d_in[7];
    const float* bq = (const float*)d_in[8];
    const float* Wk = (const float*)d_in[9];
    const float* bk = (const float*)d_in[10];
    const float* Wv = (const float*)d_in[11];
    const float* bv = (const float*)d_in[12];
    const float* Wo = (const float*)d_in[13];
    const float* bo = (const float*)d_in[14];
    const float* g1 = (const float*)d_in[15];
    const float* b1n = (const float*)d_in[16];
    const float* W1 = (const float*)d_in[17];
    const float* b1 = (const float*)d_in[18];
    const float* W2 = (const float*)d_in[19];
    const float* b2 = (const float*)d_in[20];
    const float* g2 = (const float*)d_in[21];
    const float* b2n = (const float*)d_in[22];
    const float* clsW = (const float*)d_in[23];
    const float* clsb = (const float*)d_in[24];
    float* out = (float*)d_out;

    char* ws = (char*)d_ws;
    size_t off = 0;
    auto alloc = [&](size_t n) {
        void* p = ws + off;
        off += n;
        off = (off + 255) & ~(size_t)255;
        return p;
    };
    unsigned short* hb   = (unsigned short*)alloc((size_t)TOKS * DD * 2);
    unsigned short* h1b  = (unsigned short*)alloc((size_t)TOKS * DD * 2);
    unsigned short* tmpb = (unsigned short*)alloc((size_t)TOKS * DD * 2);
    unsigned short* qkbuf = (unsigned short*)alloc((size_t)TOKS * QKW * 2);
    unsigned short* vtb  = (unsigned short*)alloc((size_t)TOKS * DD * 2);
    unsigned short* ctxb = (unsigned short*)alloc((size_t)TOKS * DD * 2);
    unsigned short* ffnb = (unsigned short*)alloc((size_t)TOKS * FF * 2);
    unsigned short* wqkvT = (unsigned short*)alloc((size_t)NQKV * DD * 2);
    unsigned short* woT = (unsigned short*)alloc((size_t)DD * DD * 2);
    unsigned short* w1T = (unsigned short*)alloc((size_t)DD * FF * 2);
    unsigned short* w2T = (unsigned short*)alloc((size_t)DD * FF * 2);
    unsigned short* clsT = (unsigned short*)alloc((size_t)VV * DD * 2);
    unsigned short* hc = (unsigned short*)alloc((size_t)NROWS * DD * 2);
    float* bqkv = (float*)alloc((size_t)LL * NQKV * 4);
    float* stS = (float*)alloc(NROWS * 4);
    float* stT = (float*)alloc(NROWS * 4);

    dim3 tb(32, 8);
    transpose_f32_bf16<<<dim3((VV + 31) / 32, DD / 32), tb, 0, stream>>>(clsW, clsT, DD, VV);
    concat_bias_all<<<(LL * NQKV + 255) / 256, 256, 0, stream>>>(bq, bk, bv, bqkv);
    embed_ln<<<TOKS, 256, 0, stream>>>(x, we, pe, te, eg, eb, hb);

    for (int l = 0; l < LL; l++) {
        transpose_layer<<<6912, tb, 0, stream>>>(Wq + (size_t)l * DD * DD, Wk + (size_t)l * DD * DD,
                                                 Wv + (size_t)l * DD * DD, Wo + (size_t)l * DD * DD,
                                                 W1 + (size_t)l * DD * FF, W2 + (size_t)l * FF * DD,
                                                 wqkvT, woT, w1T, w2T);

        gemm128<4><<<dim3(NQKV / 128, TOKS / 128), 256, 0, stream>>>(
            hb, wqkvT, bqkv + (size_t)l * NQKV,
            qkbuf, TOKS, NQKV, DD, NQKV, 8, vtb, nullptr, nullptr, nullptr);

        flash_attn<<<dim3(8, HH, BB), 256, 0, stream>>>(qkbuf, vtb, ctxb);

        gemm128<1><<<dim3(DD / 128, TOKS / 128), 256, 0, stream>>>(
            ctxb, woT, bo + (size_t)l * DD, tmpb,
            TOKS, DD, DD, DD, 8, nullptr, nullptr, nullptr, nullptr);
        add_ln<<<TOKS, 128, 0, stream>>>(hb, tmpb, g1 + (size_t)l * DD, b1n + (size_t)l * DD, h1b);

        gemm128<2><<<dim3(FF / 128, TOKS / 128), 256, 0, stream>>>(
            h1b, w1T, b1 + (size_t)l * FF, ffnb,
            TOKS, FF, DD, FF, 8, nullptr, nullptr, nullptr, nullptr);
        gemm128<1><<<dim3(DD / 128, TOKS / 128), 256, 0, stream>>>(
            ffnb, w2T, b2 + (size_t)l * DD, tmpb,
            TOKS, DD, FF, DD, 8, nullptr, nullptr, nullptr, nullptr);
        add_ln<<<TOKS, 128, 0, stream>>>(h1b, tmpb, g2 + (size_t)l * DD, b2n + (size_t)l * DD, hb);
    }

    gather_rows<<<(NROWS * (DD / 8) + 255) / 256, 256, 0, stream>>>(hb, hc, stS, stT);
    // single fused classifier GEMM + LSE; grid 166x60 = 9960 (%8==0), SM=6 (60%6==0)
    gemm128<3><<<dim3((VV + 127) / 128, NROWS / 128), 256, 0, stream>>>(hc, clsT, clsb, nullptr,
                                                                        NROWS, VV, DD, VV, 6, nullptr,
                                                                        y, stS, stT);
    final_reduce<<<1, 256, 0, stream>>>(stS, stT, y, out);
}

// Round 15
// 3843.398 us; speedup vs baseline: 1.0348x; 1.0024x over previous
//
#include <hip/hip_runtime.h>

#define BB 8
#define SS 1024
#define LL 12
#define DD 768
#define HH 12
#define FF 3072
#define VV 21128
#define DH 64
#define CLEN 960
#define NROWS (BB * CLEN)        // 7680 classifier rows
#define TOKS (BB * SS)           // 8192 token rows
#define NQKV 2304                // fused QKV output width
#define QKW 1536                 // qkbuf row width (Q|K)

typedef __attribute__((ext_vector_type(8))) short bh8;
typedef __attribute__((ext_vector_type(4))) float f32x4;
typedef __attribute__((ext_vector_type(4))) unsigned short us4;

__device__ __forceinline__ float bf2f(unsigned short u) {
    union { unsigned int i; float f; } c; c.i = ((unsigned int)u) << 16; return c.f;
}
__device__ __forceinline__ unsigned short f2bf(float f) {
    union { float f; unsigned int i; } c; c.f = f;
    unsigned int r = c.i + 0x7fffu + ((c.i >> 16) & 1u);
    return (unsigned short)(r >> 16);
}

#define GLOAD16(gsrc, ldst)                                                              \
    __builtin_amdgcn_global_load_lds((const __attribute__((address_space(1))) unsigned int*)(gsrc), \
                                     (__attribute__((address_space(3))) unsigned int*)(ldst), 16, 0, 0)

// 256-thread block sum; red must be shared float[4]
__device__ __forceinline__ float bsum256(float v, float* red) {
#pragma unroll
    for (int o = 32; o; o >>= 1) v += __shfl_down(v, o);
    if ((threadIdx.x & 63) == 0) red[threadIdx.x >> 6] = v;
    __syncthreads();
    float r = red[0] + red[1] + red[2] + red[3];
    __syncthreads();
    return r;
}

// ---------------- transpose fp32 [R,C] -> bf16 [C,R] (classifier) ----------------
__global__ void transpose_f32_bf16(const float* __restrict__ in, unsigned short* __restrict__ out,
                                   int R, int C) {
    __shared__ float tile[32][33];
    int c0 = blockIdx.x << 5, r0 = blockIdx.y << 5;
    int tx = threadIdx.x, ty = threadIdx.y;
    for (int i = ty; i < 32; i += 8) {
        int r = r0 + i, c = c0 + tx;
        if (r < R && c < C) tile[i][tx] = in[(size_t)r * C + c];
    }
    __syncthreads();
    for (int i = ty; i < 32; i += 8) {
        int oc = c0 + i, orr = r0 + tx;
        if (oc < C && orr < R) out[(size_t)oc * R + orr] = f2bf(tile[tx][i]);
    }
}

// ---------------- batched per-layer weight transpose: 1 dispatch per layer ----------------
// (kept per-layer deliberately: just-written transposed weights are L2/L3-hot when
//  the layer's GEMMs consume them — upfront transpose_all regressed R10/R11.)
__global__ void transpose_layer(const float* __restrict__ Wq, const float* __restrict__ Wk,
                                const float* __restrict__ Wv, const float* __restrict__ Wo,
                                const float* __restrict__ W1, const float* __restrict__ W2,
                                unsigned short* __restrict__ wqkvT, unsigned short* __restrict__ woT,
                                unsigned short* __restrict__ w1T, unsigned short* __restrict__ w2T) {
    __shared__ float tile[32][33];
    int t = blockIdx.x;
    const float* src;
    unsigned short* dst;
    int R, C, txt, tt;
    if (t < 1728) {
        int which = t / 576; tt = t % 576;
        src = which == 0 ? Wq : (which == 1 ? Wk : Wv);
        dst = wqkvT + (size_t)which * DD * DD; R = DD; C = DD; txt = 24;
    } else if (t < 2304) {
        tt = t - 1728; src = Wo; dst = woT; R = DD; C = DD; txt = 24;
    } else if (t < 4608) {
        tt = t - 2304; src = W1; dst = w1T; R = DD; C = FF; txt = 96;
    } else {
        tt = t - 4608; src = W2; dst = w2T; R = FF; C = DD; txt = 24;
    }
    int c0 = (tt % txt) << 5, r0 = (tt / txt) << 5;
    int tx = threadIdx.x, ty = threadIdx.y;
    for (int i = ty; i < 32; i += 8) tile[i][tx] = src[(size_t)(r0 + i) * C + c0 + tx];
    __syncthreads();
    for (int i = ty; i < 32; i += 8) dst[(size_t)(c0 + i) * R + r0 + tx] = f2bf(tile[tx][i]);
}

// all-layer QKV bias concat + classifier LSE state init
__global__ void concat_bias_all(const float* __restrict__ bq, const float* __restrict__ bk,
                                const float* __restrict__ bv, float* __restrict__ out,
                                float* __restrict__ stS, float* __restrict__ stT) {
    int i = blockIdx.x * 256 + threadIdx.x;
    if (i < NROWS) { stS[i] = 0.f; stT[i] = 0.f; }
    if (i >= LL * NQKV) return;
    int l = i / NQKV, c = i % NQKV;
    float v = c < DD ? bq[(size_t)l * DD + c]
                     : (c < 2 * DD ? bk[(size_t)l * DD + c - DD] : bv[(size_t)l * DD + c - 2 * DD]);
    out[i] = v;
}

// ---------------- embedding + LN -> bf16 (LN-out == residual stream) ----------------
__global__ __launch_bounds__(256) void embed_ln(const int* __restrict__ x, const float* __restrict__ we,
                                                const float* __restrict__ pe, const float* __restrict__ te,
                                                const float* __restrict__ g, const float* __restrict__ be,
                                                unsigned short* __restrict__ hb) {
    int row = blockIdx.x;            // b*S + s
    int s = row & (SS - 1);
    int tok = x[row];
    int tid = threadIdx.x;
    __shared__ float red[4];
    float v[3];
#pragma unroll
    for (int i = 0; i < 3; i++) {
        int c = tid + i * 256;
        v[i] = we[(size_t)tok * DD + c] + pe[(size_t)s * DD + c] + te[c];
    }
    float mean = bsum256(v[0] + v[1] + v[2], red) * (1.f / DD);
    float d0 = v[0] - mean, d1 = v[1] - mean, d2 = v[2] - mean;
    float var = bsum256(d0 * d0 + d1 * d1 + d2 * d2, red) * (1.f / DD);
    float inv = rsqrtf(var + 1e-12f);
    size_t base = (size_t)row * DD;
#pragma unroll
    for (int i = 0; i < 3; i++) {
        int c = tid + i * 256;
        hb[base + c] = f2bf((v[i] - mean) * inv * g[c] + be[c]);
    }
}

// ---------------- residual add (bf16) + LN -> bf16, vectorized; optional hc output ----------
// 128 threads/block, 96 active lanes each own 8 contiguous cols (bh8 loads/stores).
// hc != nullptr (last layer): also write compacted classifier rows (s in [64,1024)).
__global__ __launch_bounds__(128) void add_ln(const unsigned short* __restrict__ res,
                                              const unsigned short* __restrict__ t,
                                              const float* __restrict__ g, const float* __restrict__ be,
                                              unsigned short* __restrict__ outb,
                                              unsigned short* __restrict__ hc) {
    const int row = blockIdx.x;
    const int tid = threadIdx.x;
    __shared__ float red[2];
    const size_t base = (size_t)row * DD;
    float v[8];
    float s = 0.f;
    if (tid < 96) {
        bh8 a = *(const bh8*)&res[base + tid * 8];
        bh8 b = *(const bh8*)&t[base + tid * 8];
#pragma unroll
        for (int j = 0; j < 8; j++) {
            v[j] = bf2f((unsigned short)a[j]) + bf2f((unsigned short)b[j]);
            s += v[j];
        }
    }
#pragma unroll
    for (int o = 32; o; o >>= 1) s += __shfl_down(s, o);
    if ((tid & 63) == 0) red[tid >> 6] = s;
    __syncthreads();
    const float mean = (red[0] + red[1]) * (1.f / DD);
    __syncthreads();
    float vs = 0.f;
    if (tid < 96) {
#pragma unroll
        for (int j = 0; j < 8; j++) {
            float d = v[j] - mean;
            vs += d * d;
        }
    }
#pragma unroll
    for (int o = 32; o; o >>= 1) vs += __shfl_down(vs, o);
    if ((tid & 63) == 0) red[tid >> 6] = vs;
    __syncthreads();
    const float inv = rsqrtf((red[0] + red[1]) * (1.f / DD) + 1e-12f);
    if (tid < 96) {
        bh8 o8;
#pragma unroll
        for (int j = 0; j < 8; j++) {
            int c = tid * 8 + j;
            o8[j] = (short)f2bf((v[j] - mean) * inv * g[c] + be[c]);
        }
        *(bh8*)&outb[base + tid * 8] = o8;
        if (hc) {
            int ss = row & (SS - 1);
            if (ss >= 64) {
                int gr = (row >> 10) * CLEN + (ss - 64);
                *(bh8*)&hc[(size_t)gr * DD + tid * 8] = o8;
            }
        }
    }
}

// ---------------- MFMA GEMM: 128x128 tile, BK=32, double-buffered 2-phase ----------------
// Block-order remap: XCD-bijective chunk + m-bands of SM tiles walked n-major (L2 reuse).
// MODE 1: bf16 out; 2: bf16 + exact GELU; 3: fused classifier LSE; 4: fused QKV epilogue
template <int MODE>
__global__ __launch_bounds__(256) void gemm128(const unsigned short* __restrict__ A,
                                               const unsigned short* __restrict__ BT,
                                               const float* __restrict__ bias, void* __restrict__ Cp,
                                               int M, int N, int K, int ldc, int SM,
                                               unsigned short* __restrict__ vt_out,
                                               const int* __restrict__ yv,
                                               float* __restrict__ stS, float* __restrict__ stT) {
    __shared__ __align__(16) unsigned short As[2][128 * 32];
    __shared__ __align__(16) unsigned short Bs[2][128 * 32];
    const int tid = threadIdx.x;
    const int lane = tid & 63, w = tid >> 6;
    const int fr = lane & 15, fg = lane >> 4;
    const int wr = w >> 1, wc = w & 1;

    // ---- schedule remap ----
    const int Nt = gridDim.x;
    const int flat = blockIdx.y * Nt + blockIdx.x;
    const int per8 = (Nt * gridDim.y) >> 3;
    const int virt = (flat & 7) * per8 + (flat >> 3);
    const int bandSz = SM * Nt;
    const int band = virt / bandSz, rem = virt - band * bandSz;
    const int nt = rem / SM;
    const int mt = band * SM + (rem - nt * SM);
    const int m0 = mt << 7, n0 = nt << 7;

    const int srow = lane >> 2;
    const int skcol = (lane & 3) << 3;

    int arow0 = m0 + (w * 2 + 0) * 16 + srow;
    int arow1 = m0 + (w * 2 + 1) * 16 + srow;
    int brow0 = n0 + (w * 2 + 0) * 16 + srow;
    int brow1 = n0 + (w * 2 + 1) * 16 + srow;
    if (brow0 >= N) brow0 = N - 1;       // clamp (classifier tail); epilogue guarded
    if (brow1 >= N) brow1 = N - 1;
    const unsigned short* aptr0 = A + (size_t)arow0 * K + skcol;
    const unsigned short* aptr1 = A + (size_t)arow1 * K + skcol;
    const unsigned short* bptr0 = BT + (size_t)brow0 * K + skcol;
    const unsigned short* bptr1 = BT + (size_t)brow1 * K + skcol;

    auto stage = [&](int bf, int k0) {
        GLOAD16(aptr0 + k0, &As[bf][(w * 2 + 0) * 512]);
        GLOAD16(aptr1 + k0, &As[bf][(w * 2 + 1) * 512]);
        GLOAD16(bptr0 + k0, &Bs[bf][(w * 2 + 0) * 512]);
        GLOAD16(bptr1 + k0, &Bs[bf][(w * 2 + 1) * 512]);
    };

    f32x4 acc[4][4] = {};
    stage(0, 0);
    __syncthreads();      // compiler drains vmcnt(0) before barrier
    int cur = 0;
    for (int k0 = 0; k0 < K; k0 += 32) {
        if (k0 + 32 < K) stage(cur ^ 1, k0 + 32);   // prefetch overlaps compute
        bh8 a[4], b[4];
#pragma unroll
        for (int mi = 0; mi < 4; mi++) a[mi] = *(const bh8*)&As[cur][(wr * 64 + mi * 16 + fr) * 32 + fg * 8];
#pragma unroll
        for (int ni = 0; ni < 4; ni++) b[ni] = *(const bh8*)&Bs[cur][(wc * 64 + ni * 16 + fr) * 32 + fg * 8];
        __builtin_amdgcn_s_setprio(1);
#pragma unroll
        for (int mi = 0; mi < 4; mi++)
#pragma unroll
            for (int ni = 0; ni < 4; ni++)
                acc[mi][ni] = __builtin_amdgcn_mfma_f32_16x16x32_bf16(a[mi], b[ni], acc[mi][ni], 0, 0, 0);
        __builtin_amdgcn_s_setprio(0);
        __syncthreads();
        cur ^= 1;
    }

    unsigned short* Cb = (unsigned short*)Cp;
#pragma unroll
    for (int mi = 0; mi < 4; mi++) {
        int rbase = m0 + wr * 64 + mi * 16 + fg * 4;
        if (MODE == 3) {
            // fused classifier LSE: logits bounded -> max-free sumexp fp32-safe.
            float e[4] = {0.f, 0.f, 0.f, 0.f};
            int yr[4];
#pragma unroll
            for (int r = 0; r < 4; r++) yr[r] = yv[rbase + r];
#pragma unroll
            for (int ni = 0; ni < 4; ni++) {
                int col = n0 + wc * 64 + ni * 16 + fr;
                if (col < N) {
                    float bb = bias[col];
#pragma unroll
                    for (int r = 0; r < 4; r++) {
                        float v = acc[mi][ni][r] + bb;
                        e[r] += __expf(v);
                        if (col == yr[r]) stT[rbase + r] = v;   // unique writer
                    }
                }
            }
#pragma unroll
            for (int r = 0; r < 4; r++) {
#pragma unroll
                for (int off = 1; off < 16; off <<= 1) e[r] += __shfl_xor(e[r], off);
                if (fr == 0) atomicAdd(&stS[rbase + r], e[r]);
            }
        } else {
#pragma unroll
            for (int ni = 0; ni < 4; ni++) {
                int col = n0 + wc * 64 + ni * 16 + fr;
                if (MODE == 4) {
                    float bb = bias[col];
                    if (col < 2 * DD) {
#pragma unroll
                        for (int r = 0; r < 4; r++)
                            Cb[(size_t)(rbase + r) * QKW + col] = f2bf(acc[mi][ni][r] + bb);
                    } else {
                        int g = col - 2 * DD, h = g >> 6, d = g & 63;
                        int bi = rbase >> 10, s0 = rbase & 1023;
                        us4 val;
#pragma unroll
                        for (int r = 0; r < 4; r++) val[r] = f2bf(acc[mi][ni][r] + bb);
                        *(us4*)&vt_out[(((size_t)bi * HH + h) * DH + d) * SS + s0] = val;
                    }
                } else if (col < N) {
                    float bb = bias[col];
#pragma unroll
                    for (int r = 0; r < 4; r++) {
                        float v = acc[mi][ni][r] + bb;
                        if (MODE == 2) v = 0.5f * v * (1.0f + erff(v * 0.70710678118f));
                        Cb[(size_t)(rbase + r) * ldc + col] = f2bf(v);
                    }
                }
            }
        }
    }
}

// ---------------- flash attention: paired Q-tiles for perfect load balance (R12-verified) ----
// grid (8, H, B) = 768 blocks, all co-resident. Block bx handles qt = 15-bx then qt = bx
// (every block = 17 tile-steps). Pad-68 LDS (conflict-free) + T14 register prefetch.
__global__ __launch_bounds__(256) void flash_attn(const unsigned short* __restrict__ qkbuf,
                                                  const unsigned short* __restrict__ VT,
                                                  unsigned short* __restrict__ ctxb) {
    const int bx = blockIdx.x;
    const int h = blockIdx.y, b = blockIdx.z;
    const int tid = threadIdx.x;
    const int lane = tid & 63, w = tid >> 6;
    const int fr = lane & 15, fg = lane >> 4;
    __shared__ unsigned short Qs[64][68];
    __shared__ unsigned short Ks[64][68];
    __shared__ unsigned short Vt[64][68];       // Vt[d][key]
    __shared__ unsigned short Ps[4][16][68];    // per-wave P [q][key]

    const int srow = tid >> 2, sd0 = (tid & 3) << 4;
    const unsigned short* kbase = qkbuf + (size_t)(b * SS + srow) * QKW + DD + h * 64 + sd0;
    const unsigned short* vbase = VT + (((size_t)b * HH + h) * DH + srow) * SS + sd0;

    bh8 kr0, kr1, vr0, vr1;
    auto ld_reg = [&](int kt) {
        const unsigned short* ks = kbase + (size_t)(kt * 64) * QKW;
        kr0 = *(const bh8*)ks;
        kr1 = *(const bh8*)(ks + 8);
        const unsigned short* vs = vbase + kt * 64;
        vr0 = *(const bh8*)vs;
        vr1 = *(const bh8*)(vs + 8);
    };

    for (int half = 0; half < 2; half++) {
        const int qt = (half == 0) ? 15 - bx : bx;
        __syncthreads();   // protect Qs/Ks/Vt from previous half's readers
        {
            const unsigned short* src = qkbuf + (size_t)(b * SS + qt * 64 + srow) * QKW + h * 64 + sd0;
            *(bh8*)&Qs[srow][sd0] = *(const bh8*)src;
            *(bh8*)&Qs[srow][sd0 + 8] = *(const bh8*)(src + 8);
        }

        f32x4 o[4] = {};
        float m[4], l[4];
#pragma unroll
        for (int r = 0; r < 4; r++) { m[r] = -3e30f; l[r] = 0.f; }

        const int nkt = (qt == 0) ? 1 : qt + 1;
        ld_reg(0);
        for (int kt = 0; kt < nkt; kt++) {
            __syncthreads();   // (a) prev tile's LDS reads complete
            *(bh8*)&Ks[srow][sd0] = kr0;
            *(bh8*)&Ks[srow][sd0 + 8] = kr1;
            *(bh8*)&Vt[srow][sd0] = vr0;
            *(bh8*)&Vt[srow][sd0 + 8] = vr1;
            if (kt + 1 < nkt) ld_reg(kt + 1);   // in flight under this tile's compute
            __syncthreads();   // (b) Q/K/V visible

            // QK^T
            f32x4 s[4] = {};
            bh8 a0 = *(const bh8*)&Qs[w * 16 + fr][fg * 8];
            bh8 a1 = *(const bh8*)&Qs[w * 16 + fr][32 + fg * 8];
            __builtin_amdgcn_s_setprio(1);
#pragma unroll
            for (int cf = 0; cf < 4; cf++) {
                bh8 b0 = *(const bh8*)&Ks[cf * 16 + fr][fg * 8];
                bh8 b1 = *(const bh8*)&Ks[cf * 16 + fr][32 + fg * 8];
                s[cf] = __builtin_amdgcn_mfma_f32_16x16x32_bf16(a0, b0, s[cf], 0, 0, 0);
                s[cf] = __builtin_amdgcn_mfma_f32_16x16x32_bf16(a1, b1, s[cf], 0, 0, 0);
            }
            __builtin_amdgcn_s_setprio(0);

            const bool diag = (qt > 0) && (kt == qt);
#pragma unroll
            for (int cf = 0; cf < 4; cf++) {
#pragma unroll
                for (int r = 0; r < 4; r++) {
                    float v = s[cf][r] * 0.125f;
                    if (diag) {
                        int key = cf * 16 + fr;
                        int qrow = w * 16 + fg * 4 + r;
                        if (key > qrow) v = -1e30f;
                    }
                    s[cf][r] = v;
                }
            }
            float sc[4], mn[4];
#pragma unroll
            for (int r = 0; r < 4; r++) {
                float v = fmaxf(fmaxf(s[0][r], s[1][r]), fmaxf(s[2][r], s[3][r]));
#pragma unroll
                for (int off = 1; off < 16; off <<= 1) v = fmaxf(v, __shfl_xor(v, off));
                mn[r] = fmaxf(m[r], v);
                sc[r] = __expf(m[r] - mn[r]);
                m[r] = mn[r];
            }
#pragma unroll
            for (int cf = 0; cf < 4; cf++) {
#pragma unroll
                for (int r = 0; r < 4; r++) s[cf][r] = __expf(s[cf][r] - mn[r]);
            }
#pragma unroll
            for (int r = 0; r < 4; r++) {
                float v = s[0][r] + s[1][r] + s[2][r] + s[3][r];
#pragma unroll
                for (int off = 1; off < 16; off <<= 1) v += __shfl_xor(v, off);
                l[r] = l[r] * sc[r] + v;
            }
#pragma unroll
            for (int df = 0; df < 4; df++) {
#pragma unroll
                for (int r = 0; r < 4; r++) o[df][r] *= sc[r];
            }
#pragma unroll
            for (int cf = 0; cf < 4; cf++) {
#pragma unroll
                for (int r = 0; r < 4; r++) Ps[w][fg * 4 + r][cf * 16 + fr] = f2bf(s[cf][r]);
            }
            bh8 pa0 = *(const bh8*)&Ps[w][fr][fg * 8];
            bh8 pa1 = *(const bh8*)&Ps[w][fr][32 + fg * 8];
            __builtin_amdgcn_s_setprio(1);
#pragma unroll
            for (int df = 0; df < 4; df++) {
                bh8 vb0 = *(const bh8*)&Vt[df * 16 + fr][fg * 8];
                bh8 vb1 = *(const bh8*)&Vt[df * 16 + fr][32 + fg * 8];
                o[df] = __builtin_amdgcn_mfma_f32_16x16x32_bf16(pa0, vb0, o[df], 0, 0, 0);
                o[df] = __builtin_amdgcn_mfma_f32_16x16x32_bf16(pa1, vb1, o[df], 0, 0, 0);
            }
            __builtin_amdgcn_s_setprio(0);
        }
#pragma unroll
        for (int df = 0; df < 4; df++) {
#pragma unroll
            for (int r = 0; r < 4; r++) {
                int q = qt * 64 + w * 16 + fg * 4 + r;
                float v = o[df][r] / l[r];
                ctxb[(((size_t)b * SS + q) * HH + h) * DH + df * 16 + fr] = f2bf(v);
            }
        }
    }
}

__global__ __launch_bounds__(256) void final_reduce(const float* __restrict__ stS,
                                                    const float* __restrict__ stT, const int* __restrict__ y,
                                                    float* __restrict__ out) {
    int tid = threadIdx.x;
    float s = 0.f, c = 0.f;
    for (int i = tid; i < NROWS; i += 256) {
        if (y[i] != -100) {
            s += logf(stS[i]) - stT[i];
            c += 1.f;
        }
    }
    __shared__ float red[4];
    float gs = bsum256(s, red);
    float gc = bsum256(c, red);
    if (tid == 0) out[0] = gs / fmaxf(gc, 1.f);
}

// ---------------- launcher ----------------
extern "C" void kernel_launch(void* const* d_in, const int* in_sizes, int n_in,
                              void* d_out, int out_size, void* d_ws, size_t ws_size,
                              hipStream_t stream) {
    const int* x = (const int*)d_in[0];
    const int* y = (const int*)d_in[1];
    const float* we = (const float*)d_in[2];
    const float* pe = (const float*)d_in[3];
    const float* te = (const float*)d_in[4];
    const float* eg = (const float*)d_in[5];
    const float* eb = (const float*)d_in[6];
    const float* Wq = (const float*)d_in[7];
    const float* bq = (const float*)d_in[8];
    const float* Wk = (const float*)d_in[9];
    const float* bk = (const float*)d_in[10];
    const float* Wv = (const float*)d_in[11];
    const float* bv = (const float*)d_in[12];
    const float* Wo = (const float*)d_in[13];
    const float* bo = (const float*)d_in[14];
    const float* g1 = (const float*)d_in[15];
    const float* b1n = (const float*)d_in[16];
    const float* W1 = (const float*)d_in[17];
    const float* b1 = (const float*)d_in[18];
    const float* W2 = (const float*)d_in[19];
    const float* b2 = (const float*)d_in[20];
    const float* g2 = (const float*)d_in[21];
    const float* b2n = (const float*)d_in[22];
    const float* clsW = (const float*)d_in[23];
    const float* clsb = (const float*)d_in[24];
    float* out = (float*)d_out;

    char* ws = (char*)d_ws;
    size_t off = 0;
    auto alloc = [&](size_t n) {
        void* p = ws + off;
        off += n;
        off = (off + 255) & ~(size_t)255;
        return p;
    };
    unsigned short* hb   = (unsigned short*)alloc((size_t)TOKS * DD * 2);
    unsigned short* h1b  = (unsigned short*)alloc((size_t)TOKS * DD * 2);
    unsigned short* tmpb = (unsigned short*)alloc((size_t)TOKS * DD * 2);
    unsigned short* qkbuf = (unsigned short*)alloc((size_t)TOKS * QKW * 2);
    unsigned short* vtb  = (unsigned short*)alloc((size_t)TOKS * DD * 2);
    unsigned short* ctxb = (unsigned short*)alloc((size_t)TOKS * DD * 2);
    unsigned short* ffnb = (unsigned short*)alloc((size_t)TOKS * FF * 2);
    unsigned short* wqkvT = (unsigned short*)alloc((size_t)NQKV * DD * 2);
    unsigned short* woT = (unsigned short*)alloc((size_t)DD * DD * 2);
    unsigned short* w1T = (unsigned short*)alloc((size_t)DD * FF * 2);
    unsigned short* w2T = (unsigned short*)alloc((size_t)DD * FF * 2);
    unsigned short* clsT = (unsigned short*)alloc((size_t)VV * DD * 2);
    unsigned short* hc = (unsigned short*)alloc((size_t)NROWS * DD * 2);
    float* bqkv = (float*)alloc((size_t)LL * NQKV * 4);
    float* stS = (float*)alloc(NROWS * 4);
    float* stT = (float*)alloc(NROWS * 4);

    dim3 tb(32, 8);
    transpose_f32_bf16<<<dim3((VV + 31) / 32, DD / 32), tb, 0, stream>>>(clsW, clsT, DD, VV);
    concat_bias_all<<<(LL * NQKV + 255) / 256, 256, 0, stream>>>(bq, bk, bv, bqkv, stS, stT);
    embed_ln<<<TOKS, 256, 0, stream>>>(x, we, pe, te, eg, eb, hb);

    for (int l = 0; l < LL; l++) {
        transpose_layer<<<6912, tb, 0, stream>>>(Wq + (size_t)l * DD * DD, Wk + (size_t)l * DD * DD,
                                                 Wv + (size_t)l * DD * DD, Wo + (size_t)l * DD * DD,
                                                 W1 + (size_t)l * DD * FF, W2 + (size_t)l * FF * DD,
                                                 wqkvT, woT, w1T, w2T);

        gemm128<4><<<dim3(NQKV / 128, TOKS / 128), 256, 0, stream>>>(
            hb, wqkvT, bqkv + (size_t)l * NQKV,
            qkbuf, TOKS, NQKV, DD, NQKV, 8, vtb, nullptr, nullptr, nullptr);

        flash_attn<<<dim3(8, HH, BB), 256, 0, stream>>>(qkbuf, vtb, ctxb);

        gemm128<1><<<dim3(DD / 128, TOKS / 128), 256, 0, stream>>>(
            ctxb, woT, bo + (size_t)l * DD, tmpb,
            TOKS, DD, DD, DD, 8, nullptr, nullptr, nullptr, nullptr);
        add_ln<<<TOKS, 128, 0, stream>>>(hb, tmpb, g1 + (size_t)l * DD, b1n + (size_t)l * DD, h1b, nullptr);

        gemm128<2><<<dim3(FF / 128, TOKS / 128), 256, 0, stream>>>(
            h1b, w1T, b1 + (size_t)l * FF, ffnb,
            TOKS, FF, DD, FF, 8, nullptr, nullptr, nullptr, nullptr);
        gemm128<1><<<dim3(DD / 128, TOKS / 128), 256, 0, stream>>>(
            ffnb, w2T, b2 + (size_t)l * DD, tmpb,
            TOKS, DD, FF, DD, 8, nullptr, nullptr, nullptr, nullptr);
        add_ln<<<TOKS, 128, 0, stream>>>(h1b, tmpb, g2 + (size_t)l * DD, b2n + (size_t)l * DD, hb,
                                         l == LL - 1 ? hc : nullptr);
    }

    // single fused classifier GEMM + LSE; grid 166x60 = 9960 (%8==0), SM=10 (60%10==0)
    gemm128<3><<<dim3((VV + 127) / 128, NROWS / 128), 256, 0, stream>>>(hc, clsT, clsb, nullptr,
                                                                        NROWS, VV, DD, VV, 10, nullptr,
                                                                        y, stS, stT);
    final_reduce<<<1, 256, 0, stream>>>(stS, stT, y, out);
}